// Round 1
// baseline (969.299 us; speedup 1.0000x reference)
//
#include <hip/hip_runtime.h>
#include <hip/hip_bf16.h>
#include <stdint.h>

#define N_NODES 50000
#define N_EDGES 500000
#define R_REL 8
#define HID 128
#define KDIM 1152            // R*HID + HID (W-block + root-block)
#define NPAD 50048           // 391 * 128, padded row count for GEMM tiles
#define NUM_GRAPHS 64
#define NUM_CLASSES 16

// ---------- helpers ----------
__device__ __forceinline__ uint16_t f2bf(float f) {
  uint32_t u = __float_as_uint(f);
  u += 0x7FFFu + ((u >> 16) & 1u);   // RNE
  return (uint16_t)(u >> 16);
}

// ---------- edge counting sort by dst ----------
__global__ __launch_bounds__(256) void k_hist(const int* __restrict__ ei, int* __restrict__ deg) {
  int i = blockIdx.x * 256 + threadIdx.x;
  if (i < N_EDGES) atomicAdd(&deg[ei[N_EDGES + i]], 1);
}

__global__ __launch_bounds__(256) void k_scan1(const int* __restrict__ deg, int* __restrict__ offs,
                                               int* __restrict__ bsum) {
  __shared__ int sh[256];
  int t = threadIdx.x;
  int base = blockIdx.x * 1024 + t * 4;
  int v[4]; int s = 0;
  #pragma unroll
  for (int i = 0; i < 4; ++i) { int idx = base + i; v[i] = (idx < N_NODES) ? deg[idx] : 0; s += v[i]; }
  sh[t] = s;
  __syncthreads();
  for (int d = 1; d < 256; d <<= 1) {
    int add = (t >= d) ? sh[t - d] : 0;
    __syncthreads();
    sh[t] += add;
    __syncthreads();
  }
  int run = sh[t] - s;   // exclusive prefix of this thread's 4-group
  if (t == 255) bsum[blockIdx.x] = sh[255];
  #pragma unroll
  for (int i = 0; i < 4; ++i) { int idx = base + i; if (idx < N_NODES) offs[idx] = run; run += v[i]; }
}

__global__ void k_scan2(int* bsum, int nb) {
  if (threadIdx.x == 0 && blockIdx.x == 0) {
    int acc = 0;
    for (int i = 0; i < nb; ++i) { int t = bsum[i]; bsum[i] = acc; acc += t; }
  }
}

__global__ __launch_bounds__(256) void k_scan3(int* __restrict__ offs, int* __restrict__ nxt,
                                               const int* __restrict__ bsum) {
  int i = blockIdx.x * 256 + threadIdx.x;
  if (i < N_NODES) {
    int o = offs[i] + bsum[i >> 10];
    offs[i] = o;
    nxt[i] = o;
  }
  if (i == 0) offs[N_NODES] = N_EDGES;
}

__global__ __launch_bounds__(256) void k_scatter(const int* __restrict__ ei, const int* __restrict__ et,
                                                 int* __restrict__ nxt, uint32_t* __restrict__ packed) {
  int i = blockIdx.x * 256 + threadIdx.x;
  if (i < N_EDGES) {
    int dst = ei[N_EDGES + i];
    int p = atomicAdd(&nxt[dst], 1);
    packed[p] = (uint32_t)ei[i] | ((uint32_t)et[i] << 16);   // src < 2^16, rel < 8
  }
}

// ---------- per-node mean aggregation into A = [mean_r(x[src]) | x], bf16 ----------
// one wave per node; per-(rel) sums live in LDS (lane owns 2 feature slots, 2-way bank alias = free)
__global__ __launch_bounds__(256) void k_aggregate(const float* __restrict__ xin,
                                                   const uint32_t* __restrict__ packed,
                                                   const int* __restrict__ offs,
                                                   uint16_t* __restrict__ A) {
  __shared__ float lds[4][R_REL * HID];   // 16 KB
  int wave = threadIdx.x >> 6;
  int lane = threadIdx.x & 63;
  int n = blockIdx.x * 4 + wave;
  if (n >= N_NODES) return;
  float* myl = lds[wave];
  #pragma unroll
  for (int i = 0; i < (R_REL * HID) / 64; ++i) myl[i * 64 + lane] = 0.f;
  int cnt[R_REL];
  #pragma unroll
  for (int r = 0; r < R_REL; ++r) cnt[r] = 0;
  int s = offs[n], e = offs[n + 1];
  for (int j = s; j < e; ++j) {
    uint32_t p = packed[j];               // wave-uniform broadcast load
    int src = (int)(p & 0xFFFFu);
    int rel = (int)(p >> 16);
    #pragma unroll
    for (int r = 0; r < R_REL; ++r) cnt[r] += (rel == r) ? 1 : 0;
    float2 v = *(const float2*)(xin + (size_t)src * HID + lane * 2);
    float* slot = myl + rel * HID + lane * 2;
    slot[0] += v.x;
    slot[1] += v.y;
  }
  uint32_t* Arow = (uint32_t*)(A + (size_t)n * KDIM);   // write bf16 pairs
  #pragma unroll
  for (int r = 0; r < R_REL; ++r) {
    float sc = 1.0f / fmaxf((float)cnt[r], 1.0f);       // mean; empty segment -> 0
    float a0 = myl[r * HID + lane * 2] * sc;
    float a1 = myl[r * HID + lane * 2 + 1] * sc;
    Arow[r * 64 + lane] = (uint32_t)f2bf(a0) | ((uint32_t)f2bf(a1) << 16);
  }
  float2 xv = *(const float2*)(xin + (size_t)n * HID + lane * 2);
  Arow[512 + lane] = (uint32_t)f2bf(xv.x) | ((uint32_t)f2bf(xv.y) << 16);
}

// ---------- h = relu(A @ Wbar + b), fp32 vector GEMM, 128x128 tile, 8x8/thread ----------
__global__ __launch_bounds__(256) void k_gemm_relu(const uint16_t* __restrict__ A,
                                                   const float* __restrict__ Wb,
                                                   const float* __restrict__ bias,
                                                   float* __restrict__ C) {
  __shared__ float Alds[16][128];   // [k][m]
  __shared__ float Wlds[16][128];   // [k][c]
  int t = threadIdx.x;
  int m0 = (t >> 4) * 4;            // rows {m0..m0+3, m0+64..m0+67}
  int c0 = (t & 15) * 4;            // cols {c0..c0+3, c0+64..c0+67}
  int blockM = blockIdx.x * 128;
  float acc[8][8];
  #pragma unroll
  for (int i = 0; i < 8; ++i)
    #pragma unroll
    for (int j = 0; j < 8; ++j) acc[i][j] = 0.f;

  int arow = t >> 1;
  int ahalf = t & 1;
  const uint16_t* Abase = A + (size_t)(blockM + arow) * KDIM + ahalf * 8;
  float4* wdst = (float4*)&Wlds[0][0];

  for (int k0 = 0; k0 < KDIM; k0 += 16) {
    uint4 araw = *(const uint4*)(Abase + k0);   // 8 bf16
    float af[8];
    af[0] = __uint_as_float(araw.x << 16);
    af[1] = __uint_as_float(araw.x & 0xFFFF0000u);
    af[2] = __uint_as_float(araw.y << 16);
    af[3] = __uint_as_float(araw.y & 0xFFFF0000u);
    af[4] = __uint_as_float(araw.z << 16);
    af[5] = __uint_as_float(araw.z & 0xFFFF0000u);
    af[6] = __uint_as_float(araw.w << 16);
    af[7] = __uint_as_float(araw.w & 0xFFFF0000u);
    #pragma unroll
    for (int j = 0; j < 8; ++j) Alds[ahalf * 8 + j][arow] = af[j];
    const float4* wsrc = (const float4*)(Wb + k0 * 128);   // 16 contiguous rows
    wdst[t] = wsrc[t];
    wdst[t + 256] = wsrc[t + 256];
    __syncthreads();
    #pragma unroll
    for (int kk = 0; kk < 16; ++kk) {
      float4 a0 = *(const float4*)&Alds[kk][m0];
      float4 a1 = *(const float4*)&Alds[kk][m0 + 64];
      float4 w0 = *(const float4*)&Wlds[kk][c0];
      float4 w1 = *(const float4*)&Wlds[kk][c0 + 64];
      float a[8] = {a0.x, a0.y, a0.z, a0.w, a1.x, a1.y, a1.z, a1.w};
      float w[8] = {w0.x, w0.y, w0.z, w0.w, w1.x, w1.y, w1.z, w1.w};
      #pragma unroll
      for (int i = 0; i < 8; ++i)
        #pragma unroll
        for (int j = 0; j < 8; ++j) acc[i][j] += a[i] * w[j];
    }
    __syncthreads();
  }
  float4 b0 = *(const float4*)&bias[c0];
  float4 b1 = *(const float4*)&bias[c0 + 64];
  float bb[8] = {b0.x, b0.y, b0.z, b0.w, b1.x, b1.y, b1.z, b1.w};
  #pragma unroll
  for (int i = 0; i < 8; ++i) {
    int row = blockM + ((i < 4) ? (m0 + i) : (m0 + 60 + i));   // m0+64+(i-4)
    if (row < N_NODES) {
      float o[8];
      #pragma unroll
      for (int j = 0; j < 8; ++j) o[j] = fmaxf(acc[i][j] + bb[j], 0.f);
      float4 s0 = {o[0], o[1], o[2], o[3]};
      float4 s1 = {o[4], o[5], o[6], o[7]};
      *(float4*)(C + (size_t)row * HID + c0) = s0;
      *(float4*)(C + (size_t)row * HID + c0 + 64) = s1;
    }
  }
}

// ---------- pooling ----------
__global__ __launch_bounds__(256) void k_gcnt(const int* __restrict__ batch, int* __restrict__ gcnt) {
  int i = blockIdx.x * 256 + threadIdx.x;
  if (i < N_NODES) atomicAdd(&gcnt[batch[i]], 1);
}

// one wave per 64 consecutive nodes; batch is sorted -> few flushes per wave
__global__ __launch_bounds__(256) void k_pool(const float* __restrict__ h, const int* __restrict__ batch,
                                              float* __restrict__ psum) {
  int wid = (blockIdx.x * 256 + threadIdx.x) >> 6;
  int lane = threadIdx.x & 63;
  int start = wid * 64;
  if (start >= N_NODES) return;
  int end = min(start + 64, N_NODES);
  int curg = batch[start];
  float rx = 0.f, ry = 0.f;
  for (int n = start; n < end; ++n) {
    int g = batch[n];
    if (g != curg) {
      atomicAdd(&psum[curg * HID + lane * 2], rx);
      atomicAdd(&psum[curg * HID + lane * 2 + 1], ry);
      rx = ry = 0.f;
      curg = g;
    }
    float2 v = *(const float2*)(h + (size_t)n * HID + lane * 2);
    rx += v.x;
    ry += v.y;
  }
  atomicAdd(&psum[curg * HID + lane * 2], rx);
  atomicAdd(&psum[curg * HID + lane * 2 + 1], ry);
}

__global__ __launch_bounds__(256) void k_final(const float* __restrict__ psum, const int* __restrict__ gcnt,
                                               const float* __restrict__ linW, const float* __restrict__ linb,
                                               float* __restrict__ out) {
  int i = blockIdx.x * 256 + threadIdx.x;
  if (i >= NUM_GRAPHS * NUM_CLASSES) return;
  int g = i >> 4, c = i & 15;
  float inv = 1.f / fmaxf((float)gcnt[g], 1.f);
  float s = 0.f;
  for (int k = 0; k < HID; ++k) s += psum[g * HID + k] * linW[k * NUM_CLASSES + c];
  out[i] = s * inv + linb[c];   // (sum/cnt) @ linW + linb, folded: (sum@linW)*inv + linb
}

// ---------- launch ----------
extern "C" void kernel_launch(void* const* d_in, const int* in_sizes, int n_in,
                              void* d_out, int out_size, void* d_ws, size_t ws_size,
                              hipStream_t stream) {
  const float* x     = (const float*)d_in[0];
  const int*   ei    = (const int*)d_in[1];   // [2,E]: [0..E) src, [E..2E) dst
  const int*   et    = (const int*)d_in[2];
  const int*   batch = (const int*)d_in[3];
  const float* W1    = (const float*)d_in[4];
  const float* root1 = (const float*)d_in[5];
  const float* b1    = (const float*)d_in[6];
  const float* W2    = (const float*)d_in[7];
  const float* root2 = (const float*)d_in[8];
  const float* b2    = (const float*)d_in[9];
  const float* linW  = (const float*)d_in[10];
  const float* linb  = (const float*)d_in[11];
  float* out = (float*)d_out;

  char* ws = (char*)d_ws;
  size_t off = 0;
  auto alloc = [&](size_t bytes) -> char* {
    char* p = ws + off;
    off += (bytes + 255) & ~(size_t)255;
    return p;
  };
  int*      deg    = (int*)alloc((size_t)N_NODES * 4);
  int*      offs   = (int*)alloc((size_t)(N_NODES + 1) * 4);
  int*      nxt    = (int*)alloc((size_t)N_NODES * 4);
  int*      bsum   = (int*)alloc(64 * 4);
  uint32_t* packed = (uint32_t*)alloc((size_t)N_EDGES * 4);
  uint16_t* A      = (uint16_t*)alloc((size_t)NPAD * KDIM * 2);
  float*    Wbar   = (float*)alloc((size_t)KDIM * HID * 4);
  float*    h      = (float*)alloc((size_t)N_NODES * HID * 4);
  float*    psum   = (float*)alloc((size_t)NUM_GRAPHS * HID * 4);
  int*      gcnt   = (int*)alloc((size_t)NUM_GRAPHS * 4);

  hipMemsetAsync(deg, 0, (size_t)N_NODES * 4, stream);
  hipMemsetAsync(psum, 0, (size_t)NUM_GRAPHS * HID * 4, stream);
  hipMemsetAsync(gcnt, 0, (size_t)NUM_GRAPHS * 4, stream);

  int eblocks = (N_EDGES + 255) / 256;
  int nb = (N_NODES + 1023) / 1024;
  k_hist<<<eblocks, 256, 0, stream>>>(ei, deg);
  k_scan1<<<nb, 256, 0, stream>>>(deg, offs, bsum);
  k_scan2<<<1, 64, 0, stream>>>(bsum, nb);
  k_scan3<<<(N_NODES + 255) / 256, 256, 0, stream>>>(offs, nxt, bsum);
  k_scatter<<<eblocks, 256, 0, stream>>>(ei, et, nxt, packed);

  // layer 1: Wbar = [W1 (1024x128) ; root1 (128x128)]
  hipMemcpyAsync(Wbar, W1, (size_t)R_REL * HID * HID * 4, hipMemcpyDeviceToDevice, stream);
  hipMemcpyAsync(Wbar + R_REL * HID * HID, root1, (size_t)HID * HID * 4, hipMemcpyDeviceToDevice, stream);
  k_aggregate<<<(N_NODES + 3) / 4, 256, 0, stream>>>(x, packed, offs, A);
  k_gemm_relu<<<NPAD / 128, 256, 0, stream>>>(A, Wbar, b1, h);

  // layer 2 (reuses A and Wbar buffers; stream order serializes)
  hipMemcpyAsync(Wbar, W2, (size_t)R_REL * HID * HID * 4, hipMemcpyDeviceToDevice, stream);
  hipMemcpyAsync(Wbar + R_REL * HID * HID, root2, (size_t)HID * HID * 4, hipMemcpyDeviceToDevice, stream);
  k_aggregate<<<(N_NODES + 3) / 4, 256, 0, stream>>>(h, packed, offs, A);
  k_gemm_relu<<<NPAD / 128, 256, 0, stream>>>(A, Wbar, b2, h);

  // pooling + classifier
  k_gcnt<<<(N_NODES + 255) / 256, 256, 0, stream>>>(batch, gcnt);
  int waves = (N_NODES + 63) / 64;
  k_pool<<<(waves + 3) / 4, 256, 0, stream>>>(h, batch, psum);
  k_final<<<(NUM_GRAPHS * NUM_CLASSES + 255) / 256, 256, 0, stream>>>(psum, gcnt, linW, linb, out);
}

// Round 2
// 422.759 us; speedup vs baseline: 2.2928x; 2.2928x over previous
//
#include <hip/hip_runtime.h>
#include <hip/hip_bf16.h>
#include <stdint.h>

#define N_NODES 50000
#define N_EDGES 500000
#define R_REL 8
#define HID 128
#define KDIM 1152            // R*HID + HID (W-block + root-block)
#define NPAD 50048           // 391 * 128, padded row count for GEMM tiles
#define NUM_GRAPHS 64
#define NUM_CLASSES 16

typedef __attribute__((ext_vector_type(8))) short bf16x8;
typedef __attribute__((ext_vector_type(4))) float f32x4;

#define GLDS16(gp, lp) __builtin_amdgcn_global_load_lds( \
    (const __attribute__((address_space(1))) void*)(gp), \
    (__attribute__((address_space(3))) void*)(lp), 16, 0, 0)

// ---------- helpers ----------
__device__ __forceinline__ uint16_t f2bf(float f) {
  uint32_t u = __float_as_uint(f);
  u += 0x7FFFu + ((u >> 16) & 1u);   // RNE
  return (uint16_t)(u >> 16);
}

// ---------- edge counting sort by dst ----------
__global__ __launch_bounds__(256) void k_hist(const int* __restrict__ ei, int* __restrict__ deg) {
  int i = blockIdx.x * 256 + threadIdx.x;
  if (i < N_EDGES) atomicAdd(&deg[ei[N_EDGES + i]], 1);
}

__global__ __launch_bounds__(256) void k_scan1(const int* __restrict__ deg, int* __restrict__ offs,
                                               int* __restrict__ bsum) {
  __shared__ int sh[256];
  int t = threadIdx.x;
  int base = blockIdx.x * 1024 + t * 4;
  int v[4]; int s = 0;
  #pragma unroll
  for (int i = 0; i < 4; ++i) { int idx = base + i; v[i] = (idx < N_NODES) ? deg[idx] : 0; s += v[i]; }
  sh[t] = s;
  __syncthreads();
  for (int d = 1; d < 256; d <<= 1) {
    int add = (t >= d) ? sh[t - d] : 0;
    __syncthreads();
    sh[t] += add;
    __syncthreads();
  }
  int run = sh[t] - s;   // exclusive prefix of this thread's 4-group
  if (t == 255) bsum[blockIdx.x] = sh[255];
  #pragma unroll
  for (int i = 0; i < 4; ++i) { int idx = base + i; if (idx < N_NODES) offs[idx] = run; run += v[i]; }
}

__global__ void k_scan2(int* bsum, int nb) {
  if (threadIdx.x == 0 && blockIdx.x == 0) {
    int acc = 0;
    for (int i = 0; i < nb; ++i) { int t = bsum[i]; bsum[i] = acc; acc += t; }
  }
}

__global__ __launch_bounds__(256) void k_scan3(int* __restrict__ offs, int* __restrict__ nxt,
                                               const int* __restrict__ bsum) {
  int i = blockIdx.x * 256 + threadIdx.x;
  if (i < N_NODES) {
    int o = offs[i] + bsum[i >> 10];
    offs[i] = o;
    nxt[i] = o;
  }
  if (i == 0) offs[N_NODES] = N_EDGES;
}

__global__ __launch_bounds__(256) void k_scatter(const int* __restrict__ ei, const int* __restrict__ et,
                                                 int* __restrict__ nxt, uint32_t* __restrict__ packed) {
  int i = blockIdx.x * 256 + threadIdx.x;
  if (i < N_EDGES) {
    int dst = ei[N_EDGES + i];
    int p = atomicAdd(&nxt[dst], 1);
    packed[p] = (uint32_t)ei[i] | ((uint32_t)et[i] << 16);   // src < 2^16, rel < 8
  }
}

// ---------- per-node mean aggregation into A = [mean_r(x[src]) | x], bf16 ----------
__global__ __launch_bounds__(256) void k_aggregate(const float* __restrict__ xin,
                                                   const uint32_t* __restrict__ packed,
                                                   const int* __restrict__ offs,
                                                   uint16_t* __restrict__ A) {
  __shared__ float lds[4][R_REL * HID];   // 16 KB
  int wave = threadIdx.x >> 6;
  int lane = threadIdx.x & 63;
  int n = blockIdx.x * 4 + wave;
  if (n >= N_NODES) return;
  float* myl = lds[wave];
  #pragma unroll
  for (int i = 0; i < (R_REL * HID) / 64; ++i) myl[i * 64 + lane] = 0.f;
  int cnt[R_REL];
  #pragma unroll
  for (int r = 0; r < R_REL; ++r) cnt[r] = 0;
  int s = offs[n], e = offs[n + 1];
  for (int j = s; j < e; ++j) {
    uint32_t p = packed[j];               // wave-uniform broadcast load
    int src = (int)(p & 0xFFFFu);
    int rel = (int)(p >> 16);
    #pragma unroll
    for (int r = 0; r < R_REL; ++r) cnt[r] += (rel == r) ? 1 : 0;
    float2 v = *(const float2*)(xin + (size_t)src * HID + lane * 2);
    float* slot = myl + rel * HID + lane * 2;
    slot[0] += v.x;
    slot[1] += v.y;
  }
  uint32_t* Arow = (uint32_t*)(A + (size_t)n * KDIM);   // write bf16 pairs
  #pragma unroll
  for (int r = 0; r < R_REL; ++r) {
    float sc = 1.0f / fmaxf((float)cnt[r], 1.0f);       // mean; empty segment -> 0
    float a0 = myl[r * HID + lane * 2] * sc;
    float a1 = myl[r * HID + lane * 2 + 1] * sc;
    Arow[r * 64 + lane] = (uint32_t)f2bf(a0) | ((uint32_t)f2bf(a1) << 16);
  }
  float2 xv = *(const float2*)(xin + (size_t)n * HID + lane * 2);
  Arow[512 + lane] = (uint32_t)f2bf(xv.x) | ((uint32_t)f2bf(xv.y) << 16);
}

// ---------- W prep: WbT[n][k] = bf16( [W ; root][k][n] ) ----------
__global__ __launch_bounds__(256) void k_prepw(const float* __restrict__ W, const float* __restrict__ root,
                                               uint16_t* __restrict__ WbT) {
  int idx = blockIdx.x * 256 + threadIdx.x;   // n*KDIM + k
  if (idx >= HID * KDIM) return;
  int n = idx / KDIM, k = idx % KDIM;
  float v = (k < R_REL * HID) ? W[(size_t)k * HID + n] : root[(size_t)(k - R_REL * HID) * HID + n];
  WbT[idx] = f2bf(v);
}

// ---------- h = relu(A @ WbT^T + b), bf16 MFMA 16x16x32, 128x128 tile ----------
// 4 waves; wave w: rows [w*32, w*32+32), all 128 cols. acc 2x8 f32x4 frags.
__global__ __launch_bounds__(256) void k_gemm_mfma(const uint16_t* __restrict__ A,
                                                   const uint16_t* __restrict__ WbT,
                                                   const float* __restrict__ bias,
                                                   float* __restrict__ C) {
  __shared__ __align__(1024) uint16_t lds[2][128][32];   // [0]=A-tile [m][k], [1]=W-tile [n][k]; 16 KB
  int t = threadIdx.x;
  int w = t >> 6, L = t & 63;
  int quad = L >> 4, l16 = L & 15;
  int blockM = blockIdx.x * 128;

  f32x4 zero = {0.f, 0.f, 0.f, 0.f};
  f32x4 acc[2][8];
  #pragma unroll
  for (int i = 0; i < 2; ++i)
    #pragma unroll
    for (int j = 0; j < 8; ++j) acc[i][j] = zero;

  int srow = L >> 2;          // 0..15 within 16-row segment
  int selem = (L & 3) * 8;    // element offset within row (8 bf16 = 16 B)

  for (int k0 = 0; k0 < KDIM; k0 += 32) {
    #pragma unroll
    for (int q = 0; q < 2; ++q) {
      int seg = w * 2 + q;                       // 0..7 → 16 rows each
      int m = seg * 16 + srow;
      const uint16_t* ga = A + (size_t)(blockM + m) * KDIM + k0 + selem;
      GLDS16(ga, &lds[0][seg * 16][0]);          // wave-uniform base; HW adds lane*16
      const uint16_t* gw = WbT + (size_t)m * KDIM + k0 + selem;
      GLDS16(gw, &lds[1][seg * 16][0]);
    }
    __syncthreads();
    bf16x8 af[2], bfr[8];
    #pragma unroll
    for (int i = 0; i < 2; ++i)
      af[i] = *(const bf16x8*)&lds[0][w * 32 + i * 16 + l16][quad * 8];
    #pragma unroll
    for (int j = 0; j < 8; ++j)
      bfr[j] = *(const bf16x8*)&lds[1][j * 16 + l16][quad * 8];
    #pragma unroll
    for (int i = 0; i < 2; ++i)
      #pragma unroll
      for (int j = 0; j < 8; ++j)
        acc[i][j] = __builtin_amdgcn_mfma_f32_16x16x32_bf16(af[i], bfr[j], acc[i][j], 0, 0, 0);
    __syncthreads();
  }
  // epilogue: C/D layout col=lane&15, row=quad*4+reg
  #pragma unroll
  for (int i = 0; i < 2; ++i) {
    int mrow = blockM + w * 32 + i * 16 + quad * 4;
    #pragma unroll
    for (int j = 0; j < 8; ++j) {
      int c = j * 16 + l16;
      float bb = bias[c];
      #pragma unroll
      for (int r = 0; r < 4; ++r) {
        int row = mrow + r;
        if (row < N_NODES)
          C[(size_t)row * HID + c] = fmaxf(acc[i][j][r] + bb, 0.f);
      }
    }
  }
}

// ---------- graph boundaries (batch sorted) — no atomics ----------
__global__ __launch_bounds__(256) void k_bounds(const int* __restrict__ batch,
                                                int* __restrict__ gs, int* __restrict__ ge) {
  int i = blockIdx.x * 256 + threadIdx.x;
  if (i >= N_NODES) return;
  int b = batch[i];
  if (i == 0) gs[b] = 0;
  else { int pb = batch[i - 1]; if (pb != b) { ge[pb] = i; gs[b] = i; } }
  if (i == N_NODES - 1) ge[b] = N_NODES;
}

// ---------- pooled mean + classifier, one block per graph ----------
__global__ __launch_bounds__(512) void k_poolcls(const float* __restrict__ h,
                                                 const int* __restrict__ gs, const int* __restrict__ ge,
                                                 const float* __restrict__ linW, const float* __restrict__ linb,
                                                 float* __restrict__ out) {
  __shared__ float red[4][HID];
  __shared__ float pooled[HID];
  int g = blockIdx.x;
  int c = threadIdx.x & 127, ph = threadIdx.x >> 7;
  int s = gs[g], e = ge[g];
  float acc = 0.f;
  for (int n = s + ph; n < e; n += 4) acc += h[(size_t)n * HID + c];
  red[ph][c] = acc;
  __syncthreads();
  if (ph == 0) {
    float cnt = fmaxf((float)(e - s), 1.f);
    pooled[c] = (red[0][c] + red[1][c] + red[2][c] + red[3][c]) / cnt;
  }
  __syncthreads();
  if (threadIdx.x < NUM_CLASSES) {
    int cls = threadIdx.x;
    float sv = 0.f;
    #pragma unroll 8
    for (int k = 0; k < HID; ++k) sv += pooled[k] * linW[k * NUM_CLASSES + cls];
    out[g * NUM_CLASSES + cls] = sv + linb[cls];
  }
}

// ---------- launch ----------
extern "C" void kernel_launch(void* const* d_in, const int* in_sizes, int n_in,
                              void* d_out, int out_size, void* d_ws, size_t ws_size,
                              hipStream_t stream) {
  const float* x     = (const float*)d_in[0];
  const int*   ei    = (const int*)d_in[1];   // [2,E]: [0..E) src, [E..2E) dst
  const int*   et    = (const int*)d_in[2];
  const int*   batch = (const int*)d_in[3];
  const float* W1    = (const float*)d_in[4];
  const float* root1 = (const float*)d_in[5];
  const float* b1    = (const float*)d_in[6];
  const float* W2    = (const float*)d_in[7];
  const float* root2 = (const float*)d_in[8];
  const float* b2    = (const float*)d_in[9];
  const float* linW  = (const float*)d_in[10];
  const float* linb  = (const float*)d_in[11];
  float* out = (float*)d_out;

  char* ws = (char*)d_ws;
  size_t off = 0;
  auto alloc = [&](size_t bytes) -> char* {
    char* p = ws + off;
    off += (bytes + 255) & ~(size_t)255;
    return p;
  };
  int*      deg    = (int*)alloc((size_t)N_NODES * 4);
  int*      offs   = (int*)alloc((size_t)(N_NODES + 1) * 4);
  int*      nxt    = (int*)alloc((size_t)N_NODES * 4);
  int*      bsum   = (int*)alloc(64 * 4);
  uint32_t* packed = (uint32_t*)alloc((size_t)N_EDGES * 4);
  uint16_t* A      = (uint16_t*)alloc((size_t)NPAD * KDIM * 2);
  uint16_t* WbT1   = (uint16_t*)alloc((size_t)HID * KDIM * 2);
  uint16_t* WbT2   = (uint16_t*)alloc((size_t)HID * KDIM * 2);
  float*    h      = (float*)alloc((size_t)N_NODES * HID * 4);
  int*      gb     = (int*)alloc(2 * NUM_GRAPHS * 4);
  int*      gs     = gb;
  int*      ge     = gb + NUM_GRAPHS;

  hipMemsetAsync(deg, 0, (size_t)N_NODES * 4, stream);
  hipMemsetAsync(gb, 0, 2 * NUM_GRAPHS * 4, stream);

  int eblocks = (N_EDGES + 255) / 256;
  int nb = (N_NODES + 1023) / 1024;
  k_hist<<<eblocks, 256, 0, stream>>>(ei, deg);
  k_scan1<<<nb, 256, 0, stream>>>(deg, offs, bsum);
  k_scan2<<<1, 64, 0, stream>>>(bsum, nb);
  k_scan3<<<(N_NODES + 255) / 256, 256, 0, stream>>>(offs, nxt, bsum);
  k_scatter<<<eblocks, 256, 0, stream>>>(ei, et, nxt, packed);

  int wblocks = (HID * KDIM + 255) / 256;
  k_prepw<<<wblocks, 256, 0, stream>>>(W1, root1, WbT1);
  k_prepw<<<wblocks, 256, 0, stream>>>(W2, root2, WbT2);

  // layer 1
  k_aggregate<<<(N_NODES + 3) / 4, 256, 0, stream>>>(x, packed, offs, A);
  k_gemm_mfma<<<NPAD / 128, 256, 0, stream>>>(A, WbT1, b1, h);
  // layer 2
  k_aggregate<<<(N_NODES + 3) / 4, 256, 0, stream>>>(h, packed, offs, A);
  k_gemm_mfma<<<NPAD / 128, 256, 0, stream>>>(A, WbT2, b2, h);

  // pooling + classifier
  k_bounds<<<(N_NODES + 255) / 256, 256, 0, stream>>>(batch, gs, ge);
  k_poolcls<<<NUM_GRAPHS, 512, 0, stream>>>(h, gs, ge, linW, linb, out);
}